// Round 1
// baseline (211.928 us; speedup 1.0000x reference)
//
#include <hip/hip_runtime.h>
#include <hip/hip_bf16.h>

#define TN 768
#define DIM 768
#define NB 64
#define NA 51
#define POOL 128
#define THRESH 0.75f
#define LNEPS 1e-5f

typedef short s16x8 __attribute__((ext_vector_type(8)));
typedef float f32x4 __attribute__((ext_vector_type(4)));

__device__ inline unsigned short f2bf(float f) {
    union { float f; unsigned u; } v; v.f = f;
    unsigned r = v.u + 0x7fffu + ((v.u >> 16) & 1u);
    return (unsigned short)(r >> 16);
}

// ---------------- K1: per-token L2 norms (1 wave per token) ----------------
__global__ __launch_bounds__(256) void k_norms(const float* __restrict__ x,
                                               float* __restrict__ norms) {
    const int tok  = blockIdx.x * 4 + (threadIdx.x >> 6);
    const int lane = threadIdx.x & 63;
    const float4* p = (const float4*)(x + (size_t)tok * DIM);
    float s = 0.f;
#pragma unroll
    for (int q = 0; q < 3; ++q) {
        float4 v = p[q * 64 + lane];
        s += v.x * v.x + v.y * v.y + v.z * v.z + v.w * v.w;
    }
#pragma unroll
    for (int m = 1; m < 64; m <<= 1) s += __shfl_xor(s, m);
    if (lane == 0) norms[tok] = sqrtf(s);
}

// ------- K2: gram matrix tile (128x128 per block), flag sim > 0.75 ---------
__global__ __launch_bounds__(256) void k_gram(const float* __restrict__ x,
                                              const float* __restrict__ norms,
                                              int* __restrict__ bad) {
    const int it = blockIdx.x, jt = blockIdx.y, b = blockIdx.z;
    const int tid = threadIdx.x;
    __shared__ short lA[128 * 40];   // 32 bf16 cols padded to 40 (80B rows)
    __shared__ short lB[128 * 40];
    __shared__ float invA[128], invB[128];

    if (tid < 128) invA[tid] = 1.0f / norms[b * TN + jt * 128 + tid];
    else           invB[tid - 128] = 1.0f / norms[b * TN + it * 128 + (tid - 128)];
    __syncthreads();

    const float* xb = x + (size_t)b * TN * DIM;
    const int lane = tid & 63, w = tid >> 6;
    const int lr = lane & 15;
    const int lkS = (lane >> 4) * 8;   // k-chunk offset in shorts

    f32x4 zero = {0.f, 0.f, 0.f, 0.f};
    f32x4 acc[2][8];
#pragma unroll
    for (int f = 0; f < 2; ++f)
#pragma unroll
        for (int c = 0; c < 8; ++c) acc[f][c] = zero;

    for (int kk = 0; kk < 24; ++kk) {
        // stage: 128 rows x 32 cols fp32 -> normalized bf16, both tiles
#pragma unroll
        for (int pass = 0; pass < 4; ++pass) {
            int flat = pass * 256 + tid;        // 0..1023
            int row = flat >> 3, c4 = flat & 7; // row 0..127, float4-col 0..7
            const float4 va = *(const float4*)(xb + (size_t)(jt * 128 + row) * DIM + kk * 32 + c4 * 4);
            float ia = invA[row];
            ushort4 ua = { f2bf(va.x * ia), f2bf(va.y * ia), f2bf(va.z * ia), f2bf(va.w * ia) };
            *(ushort4*)&lA[row * 40 + c4 * 4] = ua;
            const float4 vb = *(const float4*)(xb + (size_t)(it * 128 + row) * DIM + kk * 32 + c4 * 4);
            float ib = invB[row];
            ushort4 ub = { f2bf(vb.x * ib), f2bf(vb.y * ib), f2bf(vb.z * ib), f2bf(vb.w * ib) };
            *(ushort4*)&lB[row * 40 + c4 * 4] = ub;
        }
        __syncthreads();
        s16x8 a0 = *(const s16x8*)&lA[(w * 32 + lr) * 40 + lkS];
        s16x8 a1 = *(const s16x8*)&lA[(w * 32 + 16 + lr) * 40 + lkS];
#pragma unroll
        for (int c = 0; c < 8; ++c) {
            s16x8 bf = *(const s16x8*)&lB[(c * 16 + lr) * 40 + lkS];
            acc[0][c] = __builtin_amdgcn_mfma_f32_16x16x32_bf16(a0, bf, acc[0][c], 0, 0, 0);
            acc[1][c] = __builtin_amdgcn_mfma_f32_16x16x32_bf16(a1, bf, acc[1][c], 0, 0, 0);
        }
        __syncthreads();
    }

    // epilogue: C/D layout (verified m89): col = lane&15, row = (lane>>4)*4 + reg
#pragma unroll
    for (int f = 0; f < 2; ++f) {
        int rowbase = jt * 128 + w * 32 + f * 16 + (lane >> 4) * 4;
#pragma unroll
        for (int r = 0; r < 4; ++r) {
            int rowg = rowbase + r;
            bool any = false;
#pragma unroll
            for (int c = 0; c < 8; ++c) {
                float v = acc[f][c][r];
                int colg = it * 128 + c * 16 + lr;
                any = any || ((v > THRESH) && (rowg != colg));
            }
            if (any) atomicOr(&bad[b * TN + rowg], 1);
        }
    }
}

// ---- K3: keep-count, top-k fallback (rank w/ index tiebreak), compaction ----
__global__ __launch_bounds__(256) void k_filter(const int* __restrict__ bad,
                                                const float* __restrict__ norms,
                                                int* __restrict__ inv,
                                                int* __restrict__ counts,
                                                int* __restrict__ Lval) {
    const int b = blockIdx.x, t = threadIdx.x;
    __shared__ float nsh[TN];
    __shared__ unsigned char ksh[TN];
    __shared__ int scan[256];

    for (int j = t; j < TN; j += 256) nsh[j] = norms[b * TN + j];
    const int j0 = t * 3;   // contiguous chunks -> stable order
#pragma unroll
    for (int q = 0; q < 3; ++q) ksh[j0 + q] = bad[b * TN + j0 + q] ? 0 : 1;
    __syncthreads();

    for (int round = 0; round < 2; ++round) {
        int local = ksh[j0] + ksh[j0 + 1] + ksh[j0 + 2];
        scan[t] = local;
        __syncthreads();
        for (int off = 1; off < 256; off <<= 1) {
            int v = (t >= off) ? scan[t - off] : 0;
            __syncthreads();
            scan[t] += v;
            __syncthreads();
        }
        int total = scan[255];                 // block-uniform
        if (round == 0 && total < POOL) {
            // fallback: top-128 by norm, ties -> lower index (matches lax.top_k)
            for (int q = 0; q < 3; ++q) {
                int j = j0 + q;
                float nj = nsh[j];
                int rank = 0;
                for (int i = 0; i < TN; ++i) {
                    float ni = nsh[i];
                    rank += (ni > nj) || (ni == nj && i < j);
                }
                ksh[j] = (rank < POOL) ? 1 : 0;
            }
            __syncthreads();
            continue;
        }
        // stable scatter of kept indices
        int pos = scan[t] - local;
        for (int q = 0; q < 3; ++q) {
            int j = j0 + q;
            if (ksh[j]) inv[b * TN + pos++] = j;
        }
        if (t == 0) { counts[b] = total; atomicMax(Lval, total); }
        break;
    }
}

// ---- K4: pooled row (only a < 51 needed) + LayerNorm + attr head dot ----
__device__ inline float block_sum(float v, volatile float* sred, int t) {
#pragma unroll
    for (int m = 1; m < 64; m <<= 1) v += __shfl_xor(v, m);
    if ((t & 63) == 0) sred[t >> 6] = v;
    __syncthreads();
    float r = sred[0] + sred[1] + sred[2] + sred[3];
    __syncthreads();
    return r;
}

__global__ __launch_bounds__(256) void k_head(const float* __restrict__ x,
                                              const int* __restrict__ inv,
                                              const int* __restrict__ counts,
                                              const int* __restrict__ Lval,
                                              const float* __restrict__ lng,
                                              const float* __restrict__ lnb,
                                              const float* __restrict__ wat,
                                              const float* __restrict__ bat,
                                              float* __restrict__ logits) {
    const int a = blockIdx.x, b = blockIdx.y, t = threadIdx.x;
    __shared__ float sred[4];
    const int L = *Lval, cnt = counts[b];
    const int start = (a * L) >> 7;
    const int end = ((a + 1) * L + 127) >> 7;   // ceil div
    const int wdt = end - start;
    const int pe = min(end, cnt);               // zeros beyond cnt contribute 0

    float a0 = 0.f, a1 = 0.f, a2 = 0.f;
    for (int p = start; p < pe; ++p) {
        const float* row = x + (size_t)(b * TN + inv[b * TN + p]) * DIM;
        a0 += row[t]; a1 += row[t + 256]; a2 += row[t + 512];
    }
    const float iw = 1.0f / (float)wdt;
    a0 *= iw; a1 *= iw; a2 *= iw;

    float s1 = block_sum(a0 + a1 + a2, sred, t);
    float s2 = block_sum(a0 * a0 + a1 * a1 + a2 * a2, sred, t);
    const float mu = s1 * (1.0f / 768.0f);
    const float var = s2 * (1.0f / 768.0f) - mu * mu;
    const float rstd = rsqrtf(var + LNEPS);

    const float* wa = wat + (size_t)a * DIM;
    float d = ((a0 - mu) * rstd * lng[t]       + lnb[t])       * wa[t]
            + ((a1 - mu) * rstd * lng[t + 256] + lnb[t + 256]) * wa[t + 256]
            + ((a2 - mu) * rstd * lng[t + 512] + lnb[t + 512]) * wa[t + 512];
    float dot = block_sum(d, sred, t);
    if (t == 0) logits[b * NA + a] = dot + bat[a];
}

// ---------------- K5: BatchNorm1d over batch (training stats) ----------------
__global__ __launch_bounds__(64) void k_bn(const float* __restrict__ logits,
                                           const float* __restrict__ bng,
                                           const float* __restrict__ bnb,
                                           float* __restrict__ out) {
    const int a = threadIdx.x;
    if (a >= NA) return;
    float s = 0.f, s2 = 0.f;
    for (int b = 0; b < NB; ++b) {
        float v = logits[b * NA + a];
        s += v; s2 += v * v;
    }
    const float m = s * (1.0f / 64.0f);
    const float var = s2 * (1.0f / 64.0f) - m * m;
    const float rstd = rsqrtf(var + LNEPS);
    const float ga = bng[a], be = bnb[a];
    for (int b = 0; b < NB; ++b)
        out[b * NA + a] = (logits[b * NA + a] - m) * rstd * ga + be;
}

extern "C" void kernel_launch(void* const* d_in, const int* in_sizes, int n_in,
                              void* d_out, int out_size, void* d_ws, size_t ws_size,
                              hipStream_t stream) {
    const float* x     = (const float*)d_in[0];
    const float* ln_g  = (const float*)d_in[1];
    const float* ln_b  = (const float*)d_in[2];
    const float* w_at  = (const float*)d_in[3];
    const float* b_at  = (const float*)d_in[4];
    const float* bn_g  = (const float*)d_in[5];
    const float* bn_b  = (const float*)d_in[6];
    float* out = (float*)d_out;

    char* wsc = (char*)d_ws;
    float* norms  = (float*)(wsc);             // 49152 f32 = 196608 B
    int*   bad    = (int*)(wsc + 196608);      // 49152 i32
    int*   inv    = (int*)(wsc + 393216);      // 49152 i32
    int*   counts = (int*)(wsc + 589824);      // 64 i32 (pad to 256)
    int*   Lval   = (int*)(wsc + 590080);      // 1 i32 (pad to 256)
    float* logits = (float*)(wsc + 590336);    // 3264 f32

    hipMemsetAsync(bad, 0, 196608, stream);
    hipMemsetAsync(Lval, 0, 4, stream);

    k_norms <<<NB * TN / 4, 256, 0, stream>>>(x, norms);
    k_gram  <<<dim3(6, 6, NB), 256, 0, stream>>>(x, norms, bad);
    k_filter<<<NB, 256, 0, stream>>>(bad, norms, inv, counts, Lval);
    k_head  <<<dim3(NA, NB), 256, 0, stream>>>(x, inv, counts, Lval,
                                               ln_g, ln_b, w_at, b_at, logits);
    k_bn    <<<1, 64, 0, stream>>>(logits, bn_g, bn_b, out);
}

// Round 2
// 105.540 us; speedup vs baseline: 2.0080x; 2.0080x over previous
//
#include <hip/hip_runtime.h>
#include <hip/hip_bf16.h>

#define TN 768
#define DIM 768
#define NB 64
#define NA 51
#define POOL 128
#define THRESH 0.75f
#define LNEPS 1e-5f

typedef short s16x8 __attribute__((ext_vector_type(8)));
typedef float f32x4 __attribute__((ext_vector_type(4)));

typedef const __attribute__((address_space(1))) unsigned int* gas_p;
typedef __attribute__((address_space(3))) unsigned int* las_p;

__device__ __forceinline__ void gload16(const void* g, void* l) {
    // dest = lds base + lane*16 (wave-uniform base); src is per-lane
    __builtin_amdgcn_global_load_lds((gas_p)g, (las_p)l, 16, 0, 0);
}

__device__ inline unsigned short f2bf(float f) {
    union { float f; unsigned u; } v; v.f = f;
    unsigned r = v.u + 0x7fffu + ((v.u >> 16) & 1u);
    return (unsigned short)(r >> 16);
}

__constant__ int PAIR_I[21] = {0,1,1,2,2,2,3,3,3,3,4,4,4,4,4,5,5,5,5,5,5};
__constant__ int PAIR_J[21] = {0,0,1,0,1,2,0,1,2,3,0,1,2,3,4,0,1,2,3,4,5};

// ---- K1: per-token L2 norm + normalized bf16 copy (1 wave per token) ----
__global__ __launch_bounds__(256) void k_norms(const float* __restrict__ x,
                                               unsigned short* __restrict__ xn,
                                               float* __restrict__ norms) {
    const int tok  = blockIdx.x * 4 + (threadIdx.x >> 6);
    const int lane = threadIdx.x & 63;
    const float4* p = (const float4*)(x + (size_t)tok * DIM);
    float4 v[3];
    float s = 0.f;
#pragma unroll
    for (int q = 0; q < 3; ++q) {
        v[q] = p[q * 64 + lane];
        s += v[q].x * v[q].x + v[q].y * v[q].y + v[q].z * v[q].z + v[q].w * v[q].w;
    }
#pragma unroll
    for (int m = 1; m < 64; m <<= 1) s += __shfl_xor(s, m);
    const float nrm = sqrtf(s);
    const float sc = 1.0f / nrm;
#pragma unroll
    for (int q = 0; q < 3; ++q) {
        ushort4 u = { f2bf(v[q].x * sc), f2bf(v[q].y * sc),
                      f2bf(v[q].z * sc), f2bf(v[q].w * sc) };
        *(ushort4*)&xn[(size_t)tok * DIM + q * 256 + lane * 4] = u;
    }
    if (lane == 0) norms[tok] = nrm;
}

// ---- K2: gram tiles, triangle only (21 pairs), bf16 in, flag sim>0.75 ----
__global__ __launch_bounds__(256) void k_gram(const unsigned short* __restrict__ xn,
                                              int* __restrict__ bad) {
    // bijective XCD swizzle: 1344 blocks = 8 XCD x 168; same-b blocks cluster
    const int f = blockIdx.x;
    const int lid = (f & 7) * 168 + (f >> 3);
    const int b = lid / 21, p = lid - b * 21;
    const int it = PAIR_I[p], jt = PAIR_J[p];
    const bool diag = (it == jt);

    const int tid = threadIdx.x;
    const int lane = tid & 63, w = tid >> 6;
    const int lr = lane & 15;

    __shared__ alignas(16) unsigned short lA[128 * 64];   // 16 KB, linear, XOR-swizzled content
    __shared__ alignas(16) unsigned short lB[128 * 64];

    const char* xb = (const char*)(xn + (size_t)b * TN * DIM);
    // staging geometry: each 1KB LDS segment = 8 rows x 128B; lane l writes
    // bytes [l*16, l*16+16) of the segment -> row srow, granule (l&7).
    // Swizzled read addr is row*128 + 16*(g ^ (row&7)); XOR is an involution,
    // so stage from source granule sg = (l&7) ^ (srow&7) into linear dest.
    const int srow = lane >> 3;                       // row within 8-row segment
    const int sgoff = 16 * ((lane & 7) ^ (srow & 7)); // swizzled source byte off

    f32x4 acc[2][8];
#pragma unroll
    for (int ff = 0; ff < 2; ++ff)
#pragma unroll
        for (int c = 0; c < 8; ++c) acc[ff][c] = {0.f, 0.f, 0.f, 0.f};

    for (int kk = 0; kk < 12; ++kk) {
#pragma unroll
        for (int i = 0; i < 4; ++i) {
            const int seg = w * 4 + i;
            const int rowA = jt * 128 + seg * 8 + srow;
            gload16(xb + (size_t)rowA * 1536 + kk * 128 + sgoff,
                    (char*)lA + seg * 1024);
        }
        if (!diag) {
#pragma unroll
            for (int i = 0; i < 4; ++i) {
                const int seg = w * 4 + i;
                const int rowB = it * 128 + seg * 8 + srow;
                gload16(xb + (size_t)rowB * 1536 + kk * 128 + sgoff,
                        (char*)lB + seg * 1024);
            }
        }
        asm volatile("s_waitcnt vmcnt(0)" ::: "memory");
        __syncthreads();

        const unsigned short* Bs = diag ? lA : lB;
        const int gx = 8 * (lr & 7);   // XOR term (r&7)==lr&7 for all frag rows
#pragma unroll
        for (int kkk = 0; kkk < 2; ++kkk) {
            const int g = kkk * 4 + (lane >> 4);
            const int gs = (8 * g) ^ gx;                 // short offset within row
            const int r0 = w * 32 + lr;
            s16x8 a0 = *(const s16x8*)&lA[r0 * 64 + gs];
            s16x8 a1 = *(const s16x8*)&lA[(r0 + 16) * 64 + gs];
#pragma unroll
            for (int c = 0; c < 8; ++c) {
                s16x8 bf = *(const s16x8*)&Bs[(c * 16 + lr) * 64 + gs];
                acc[0][c] = __builtin_amdgcn_mfma_f32_16x16x32_bf16(a0, bf, acc[0][c], 0, 0, 0);
                acc[1][c] = __builtin_amdgcn_mfma_f32_16x16x32_bf16(a1, bf, acc[1][c], 0, 0, 0);
            }
        }
        __syncthreads();
    }

    // C/D layout: col = lane&15, row = (lane>>4)*4 + reg   [m89/m91]
#pragma unroll
    for (int ff = 0; ff < 2; ++ff) {
#pragma unroll
        for (int r = 0; r < 4; ++r) {
            const int rowg = jt * 128 + w * 32 + ff * 16 + (lane >> 4) * 4 + r;
            bool any = false;
#pragma unroll
            for (int c = 0; c < 8; ++c) {
                const int colg = it * 128 + c * 16 + lr;
                any = any || (acc[ff][c][r] > THRESH && rowg != colg);
            }
            if (any) bad[b * TN + rowg] = 1;   // benign race: all writers store 1
        }
    }
    if (!diag) {   // symmetry: flag columns too (their row view is this tile^T)
#pragma unroll
        for (int c = 0; c < 8; ++c) {
            const int colg = it * 128 + c * 16 + lr;
            bool any = false;
#pragma unroll
            for (int ff = 0; ff < 2; ++ff)
#pragma unroll
                for (int r = 0; r < 4; ++r)
                    any = any || (acc[ff][c][r] > THRESH);
            if (any) bad[b * TN + colg] = 1;
        }
    }
}

// ---- K3: keep-count, top-k fallback (rank w/ index tiebreak), compaction ----
__global__ __launch_bounds__(256) void k_filter(const int* __restrict__ bad,
                                                const float* __restrict__ norms,
                                                int* __restrict__ inv,
                                                int* __restrict__ counts,
                                                int* __restrict__ Lval) {
    const int b = blockIdx.x, t = threadIdx.x;
    __shared__ float nsh[TN];
    __shared__ unsigned char ksh[TN];
    __shared__ int scan[256];

    for (int j = t; j < TN; j += 256) nsh[j] = norms[b * TN + j];
    const int j0 = t * 3;
#pragma unroll
    for (int q = 0; q < 3; ++q) ksh[j0 + q] = bad[b * TN + j0 + q] ? 0 : 1;
    __syncthreads();

    for (int round = 0; round < 2; ++round) {
        int local = ksh[j0] + ksh[j0 + 1] + ksh[j0 + 2];
        scan[t] = local;
        __syncthreads();
        for (int off = 1; off < 256; off <<= 1) {
            int v = (t >= off) ? scan[t - off] : 0;
            __syncthreads();
            scan[t] += v;
            __syncthreads();
        }
        int total = scan[255];
        if (round == 0 && total < POOL) {
            for (int q = 0; q < 3; ++q) {
                int j = j0 + q;
                float nj = nsh[j];
                int rank = 0;
                for (int i = 0; i < TN; ++i) {
                    float ni = nsh[i];
                    rank += (ni > nj) || (ni == nj && i < j);
                }
                ksh[j] = (rank < POOL) ? 1 : 0;
            }
            __syncthreads();
            continue;
        }
        int pos = scan[t] - local;
        for (int q = 0; q < 3; ++q) {
            int j = j0 + q;
            if (ksh[j]) inv[b * TN + pos++] = j;
        }
        if (t == 0) { counts[b] = total; atomicMax(Lval, total); }
        break;
    }
}

// ---- K4: pooled row (only a < 51 needed) + LayerNorm + attr head dot ----
__device__ inline float block_sum(float v, volatile float* sred, int t) {
#pragma unroll
    for (int m = 1; m < 64; m <<= 1) v += __shfl_xor(v, m);
    if ((t & 63) == 0) sred[t >> 6] = v;
    __syncthreads();
    float r = sred[0] + sred[1] + sred[2] + sred[3];
    __syncthreads();
    return r;
}

__global__ __launch_bounds__(256) void k_head(const float* __restrict__ x,
                                              const int* __restrict__ inv,
                                              const int* __restrict__ counts,
                                              const int* __restrict__ Lval,
                                              const float* __restrict__ lng,
                                              const float* __restrict__ lnb,
                                              const float* __restrict__ wat,
                                              const float* __restrict__ bat,
                                              float* __restrict__ logits) {
    const int a = blockIdx.x, b = blockIdx.y, t = threadIdx.x;
    __shared__ float sred[4];
    const int L = *Lval, cnt = counts[b];
    const int start = (a * L) >> 7;
    const int end = ((a + 1) * L + 127) >> 7;
    const int wdt = end - start;
    const int pe = min(end, cnt);

    float a0 = 0.f, a1 = 0.f, a2 = 0.f;
    for (int p = start; p < pe; ++p) {
        const float* row = x + (size_t)(b * TN + inv[b * TN + p]) * DIM;
        a0 += row[t]; a1 += row[t + 256]; a2 += row[t + 512];
    }
    const float iw = 1.0f / (float)wdt;
    a0 *= iw; a1 *= iw; a2 *= iw;

    float s1 = block_sum(a0 + a1 + a2, sred, t);
    float s2 = block_sum(a0 * a0 + a1 * a1 + a2 * a2, sred, t);
    const float mu = s1 * (1.0f / 768.0f);
    const float var = s2 * (1.0f / 768.0f) - mu * mu;
    const float rstd = rsqrtf(var + LNEPS);

    const float* wa = wat + (size_t)a * DIM;
    float d = ((a0 - mu) * rstd * lng[t]       + lnb[t])       * wa[t]
            + ((a1 - mu) * rstd * lng[t + 256] + lnb[t + 256]) * wa[t + 256]
            + ((a2 - mu) * rstd * lng[t + 512] + lnb[t + 512]) * wa[t + 512];
    float dot = block_sum(d, sred, t);
    if (t == 0) logits[b * NA + a] = dot + bat[a];
}

// ---------------- K5: BatchNorm1d over batch (training stats) ----------------
__global__ __launch_bounds__(64) void k_bn(const float* __restrict__ logits,
                                           const float* __restrict__ bng,
                                           const float* __restrict__ bnb,
                                           float* __restrict__ out) {
    const int a = threadIdx.x;
    if (a >= NA) return;
    float s = 0.f, s2 = 0.f;
    for (int b = 0; b < NB; ++b) {
        float v = logits[b * NA + a];
        s += v; s2 += v * v;
    }
    const float m = s * (1.0f / 64.0f);
    const float var = s2 * (1.0f / 64.0f) - m * m;
    const float rstd = rsqrtf(var + LNEPS);
    const float ga = bng[a], be = bnb[a];
    for (int b = 0; b < NB; ++b)
        out[b * NA + a] = (logits[b * NA + a] - m) * rstd * ga + be;
}

extern "C" void kernel_launch(void* const* d_in, const int* in_sizes, int n_in,
                              void* d_out, int out_size, void* d_ws, size_t ws_size,
                              hipStream_t stream) {
    const float* x     = (const float*)d_in[0];
    const float* ln_g  = (const float*)d_in[1];
    const float* ln_b  = (const float*)d_in[2];
    const float* w_at  = (const float*)d_in[3];
    const float* b_at  = (const float*)d_in[4];
    const float* bn_g  = (const float*)d_in[5];
    const float* bn_b  = (const float*)d_in[6];
    float* out = (float*)d_out;

    char* wsc = (char*)d_ws;
    const size_t XN = 64ull * 768 * 768 * 2;          // 75,497,472 B bf16 copy
    unsigned short* xn = (unsigned short*)wsc;
    float* norms  = (float*)(wsc + XN);                // 196608 B
    int*   bad    = (int*)(wsc + XN + 196608);         // 196608 B
    int*   inv    = (int*)(wsc + XN + 393216);         // 196608 B
    int*   counts = (int*)(wsc + XN + 589824);         // 256 B
    int*   Lval   = (int*)(wsc + XN + 590080);         // 256 B
    float* logits = (float*)(wsc + XN + 590336);       // 13056 B

    hipMemsetAsync(bad, 0, 196608, stream);
    hipMemsetAsync(Lval, 0, 4, stream);

    k_norms <<<NB * TN / 4, 256, 0, stream>>>(x, xn, norms);
    k_gram  <<<21 * NB, 256, 0, stream>>>(xn, bad);
    k_filter<<<NB, 256, 0, stream>>>(bad, norms, inv, counts, Lval);
    k_head  <<<dim3(NA, NB), 256, 0, stream>>>(x, inv, counts, Lval,
                                               ln_g, ln_b, w_at, b_at, logits);
    k_bn    <<<1, 64, 0, stream>>>(logits, bn_g, bn_b, out);
}

// Round 3
// 98.783 us; speedup vs baseline: 2.1454x; 1.0684x over previous
//
#include <hip/hip_runtime.h>
#include <hip/hip_bf16.h>

#define TN 768
#define DIM 768
#define NB 64
#define NA 51
#define POOL 128
#define THRESH 0.75f
#define LNEPS 1e-5f

typedef short s16x8 __attribute__((ext_vector_type(8)));
typedef float f32x4 __attribute__((ext_vector_type(4)));

typedef const __attribute__((address_space(1))) unsigned int* gas_p;
typedef __attribute__((address_space(3))) unsigned int* las_p;

__device__ __forceinline__ void gload16(const void* g, void* l) {
    // dest = lds base + lane*16 (wave-uniform base); src is per-lane
    __builtin_amdgcn_global_load_lds((gas_p)g, (las_p)l, 16, 0, 0);
}

__device__ inline unsigned short f2bf(float f) {
    union { float f; unsigned u; } v; v.f = f;
    unsigned r = v.u + 0x7fffu + ((v.u >> 16) & 1u);
    return (unsigned short)(r >> 16);
}

__constant__ int PAIR_I[21] = {0,1,1,2,2,2,3,3,3,3,4,4,4,4,4,5,5,5,5,5,5};
__constant__ int PAIR_J[21] = {0,0,1,0,1,2,0,1,2,3,0,1,2,3,4,0,1,2,3,4,5};

// ---- K1: per-token L2 norm + normalized bf16 copy (1 wave per token) ----
//      also zeroes bad[] and Lval (replaces two memset dispatches)
__global__ __launch_bounds__(256) void k_norms(const float* __restrict__ x,
                                               unsigned short* __restrict__ xn,
                                               float* __restrict__ norms,
                                               int* __restrict__ bad,
                                               int* __restrict__ Lval) {
    if (blockIdx.x < 192) bad[blockIdx.x * 256 + threadIdx.x] = 0;
    if (blockIdx.x == 0 && threadIdx.x == 0) *Lval = 0;

    const int tok  = blockIdx.x * 4 + (threadIdx.x >> 6);
    const int lane = threadIdx.x & 63;
    const float4* p = (const float4*)(x + (size_t)tok * DIM);
    float4 v[3];
    float s = 0.f;
#pragma unroll
    for (int q = 0; q < 3; ++q) {
        v[q] = p[q * 64 + lane];
        s += v[q].x * v[q].x + v[q].y * v[q].y + v[q].z * v[q].z + v[q].w * v[q].w;
    }
#pragma unroll
    for (int m = 1; m < 64; m <<= 1) s += __shfl_xor(s, m);
    const float nrm = sqrtf(s);
    const float sc = 1.0f / nrm;
#pragma unroll
    for (int q = 0; q < 3; ++q) {
        ushort4 u = { f2bf(v[q].x * sc), f2bf(v[q].y * sc),
                      f2bf(v[q].z * sc), f2bf(v[q].w * sc) };
        *(ushort4*)&xn[(size_t)tok * DIM + q * 256 + lane * 4] = u;
    }
    if (lane == 0) norms[tok] = nrm;
}

// ---- K2: gram tiles, triangle only (21 pairs), 2-phase dbuf pipeline ----
__global__ __launch_bounds__(256) void k_gram(const unsigned short* __restrict__ xn,
                                              int* __restrict__ bad) {
    // bijective XCD swizzle: 1344 blocks = 8 XCD x 168; same-b blocks cluster
    const int f = blockIdx.x;
    const int lid = (f & 7) * 168 + (f >> 3);
    const int b = lid / 21, p = lid - b * 21;
    const int it = PAIR_I[p], jt = PAIR_J[p];
    const bool diag = (it == jt);

    const int tid = threadIdx.x;
    const int lane = tid & 63, w = tid >> 6;
    const int lr = lane & 15;

    __shared__ alignas(16) unsigned short lA[2][128 * 64];   // 2 x 16 KB
    __shared__ alignas(16) unsigned short lB[2][128 * 64];

    const char* xb = (const char*)(xn + (size_t)b * TN * DIM);
    // staging: each 1KB LDS segment = 8 rows x 128B; lane l -> row srow,
    // granule (l&7). Swizzled read addr = row*128 + 16*(g ^ (row&7)); XOR is
    // an involution, so pre-swizzle the global source, keep LDS dest linear.
    const int srow = lane >> 3;
    const int sgoff = 16 * ((lane & 7) ^ (srow & 7));
    const size_t baseA = (size_t)(jt * 128 + srow) * 1536 + sgoff;
    const size_t baseB = (size_t)(it * 128 + srow) * 1536 + sgoff;

    f32x4 acc[2][8];
#pragma unroll
    for (int ff = 0; ff < 2; ++ff)
#pragma unroll
        for (int c = 0; c < 8; ++c) acc[ff][c] = {0.f, 0.f, 0.f, 0.f};

    auto stage = [&](int bb, int kk) {
#pragma unroll
        for (int i = 0; i < 4; ++i) {
            const int seg = w * 4 + i;
            gload16(xb + baseA + (size_t)seg * 8 * 1536 + kk * 128,
                    (char*)lA[bb] + seg * 1024);
        }
        if (!diag) {
#pragma unroll
            for (int i = 0; i < 4; ++i) {
                const int seg = w * 4 + i;
                gload16(xb + baseB + (size_t)seg * 8 * 1536 + kk * 128,
                        (char*)lB[bb] + seg * 1024);
            }
        }
    };

    auto compute = [&](int bb) {
        const unsigned short* As = lA[bb];
        const unsigned short* Bs = diag ? lA[bb] : lB[bb];
        const int gx = 8 * (lr & 7);   // XOR term (r&7)==lr&7 for all frag rows
#pragma unroll
        for (int kkk = 0; kkk < 2; ++kkk) {
            const int g = kkk * 4 + (lane >> 4);
            const int gs = (8 * g) ^ gx;
            const int r0 = w * 32 + lr;
            s16x8 a0 = *(const s16x8*)&As[r0 * 64 + gs];
            s16x8 a1 = *(const s16x8*)&As[(r0 + 16) * 64 + gs];
#pragma unroll
            for (int c = 0; c < 8; ++c) {
                s16x8 bf = *(const s16x8*)&Bs[(c * 16 + lr) * 64 + gs];
                acc[0][c] = __builtin_amdgcn_mfma_f32_16x16x32_bf16(a0, bf, acc[0][c], 0, 0, 0);
                acc[1][c] = __builtin_amdgcn_mfma_f32_16x16x32_bf16(a1, bf, acc[1][c], 0, 0, 0);
            }
        }
    };

    // 2-phase pipeline: stage(next) || compute(cur); one vmcnt(0)+barrier/step
    stage(0, 0);
    asm volatile("s_waitcnt vmcnt(0)" ::: "memory");
    __builtin_amdgcn_s_barrier();
#pragma unroll 2
    for (int kk = 0; kk < 12; ++kk) {
        const int cur = kk & 1;
        if (kk < 11) stage(cur ^ 1, kk + 1);
        compute(cur);
        if (kk < 11) {
            asm volatile("s_waitcnt vmcnt(0)" ::: "memory");
            __builtin_amdgcn_s_barrier();
        }
    }

    // C/D layout: col = lane&15, row = (lane>>4)*4 + reg   [m89/m91]
#pragma unroll
    for (int ff = 0; ff < 2; ++ff) {
#pragma unroll
        for (int r = 0; r < 4; ++r) {
            const int rowg = jt * 128 + w * 32 + ff * 16 + (lane >> 4) * 4 + r;
            bool any = false;
#pragma unroll
            for (int c = 0; c < 8; ++c) {
                const int colg = it * 128 + c * 16 + lr;
                any = any || (acc[ff][c][r] > THRESH && rowg != colg);
            }
            if (any) bad[b * TN + rowg] = 1;   // benign race: all writers store 1
        }
    }
    if (!diag) {   // symmetry: flag columns too (their row view is this tile^T)
#pragma unroll
        for (int c = 0; c < 8; ++c) {
            const int colg = it * 128 + c * 16 + lr;
            bool any = false;
#pragma unroll
            for (int ff = 0; ff < 2; ++ff)
#pragma unroll
                for (int r = 0; r < 4; ++r)
                    any = any || (acc[ff][c][r] > THRESH);
            if (any) bad[b * TN + colg] = 1;
        }
    }
}

// ---- K3: keep-count, top-k fallback (rank w/ index tiebreak), compaction ----
__global__ __launch_bounds__(256) void k_filter(const int* __restrict__ bad,
                                                const float* __restrict__ norms,
                                                int* __restrict__ inv,
                                                int* __restrict__ counts,
                                                int* __restrict__ Lval) {
    const int b = blockIdx.x, t = threadIdx.x;
    __shared__ float nsh[TN];
    __shared__ unsigned char ksh[TN];
    __shared__ int scan[256];

    for (int j = t; j < TN; j += 256) nsh[j] = norms[b * TN + j];
    const int j0 = t * 3;
#pragma unroll
    for (int q = 0; q < 3; ++q) ksh[j0 + q] = bad[b * TN + j0 + q] ? 0 : 1;
    __syncthreads();

    for (int round = 0; round < 2; ++round) {
        int local = ksh[j0] + ksh[j0 + 1] + ksh[j0 + 2];
        scan[t] = local;
        __syncthreads();
        for (int off = 1; off < 256; off <<= 1) {
            int v = (t >= off) ? scan[t - off] : 0;
            __syncthreads();
            scan[t] += v;
            __syncthreads();
        }
        int total = scan[255];
        if (round == 0 && total < POOL) {
            for (int q = 0; q < 3; ++q) {
                int j = j0 + q;
                float nj = nsh[j];
                int rank = 0;
                for (int i = 0; i < TN; ++i) {
                    float ni = nsh[i];
                    rank += (ni > nj) || (ni == nj && i < j);
                }
                ksh[j] = (rank < POOL) ? 1 : 0;
            }
            __syncthreads();
            continue;
        }
        int pos = scan[t] - local;
        for (int q = 0; q < 3; ++q) {
            int j = j0 + q;
            if (ksh[j]) inv[b * TN + pos++] = j;
        }
        if (t == 0) { counts[b] = total; atomicMax(Lval, total); }
        break;
    }
}

// ---- K4: pooled row (only a < 51 needed) + LayerNorm + attr head dot ----
__device__ inline float block_sum(float v, volatile float* sred, int t) {
#pragma unroll
    for (int m = 1; m < 64; m <<= 1) v += __shfl_xor(v, m);
    if ((t & 63) == 0) sred[t >> 6] = v;
    __syncthreads();
    float r = sred[0] + sred[1] + sred[2] + sred[3];
    __syncthreads();
    return r;
}

__global__ __launch_bounds__(256) void k_head(const float* __restrict__ x,
                                              const int* __restrict__ inv,
                                              const int* __restrict__ counts,
                                              const int* __restrict__ Lval,
                                              const float* __restrict__ lng,
                                              const float* __restrict__ lnb,
                                              const float* __restrict__ wat,
                                              const float* __restrict__ bat,
                                              float* __restrict__ logits) {
    const int a = blockIdx.x, b = blockIdx.y, t = threadIdx.x;
    __shared__ float sred[4];
    const int L = *Lval, cnt = counts[b];
    const int start = (a * L) >> 7;
    const int end = ((a + 1) * L + 127) >> 7;
    const int wdt = end - start;
    const int pe = min(end, cnt);

    float a0 = 0.f, a1 = 0.f, a2 = 0.f;
    for (int p = start; p < pe; ++p) {
        const float* row = x + (size_t)(b * TN + inv[b * TN + p]) * DIM;
        a0 += row[t]; a1 += row[t + 256]; a2 += row[t + 512];
    }
    const float iw = 1.0f / (float)wdt;
    a0 *= iw; a1 *= iw; a2 *= iw;

    float s1 = block_sum(a0 + a1 + a2, sred, t);
    float s2 = block_sum(a0 * a0 + a1 * a1 + a2 * a2, sred, t);
    const float mu = s1 * (1.0f / 768.0f);
    const float var = s2 * (1.0f / 768.0f) - mu * mu;
    const float rstd = rsqrtf(var + LNEPS);

    const float* wa = wat + (size_t)a * DIM;
    float d = ((a0 - mu) * rstd * lng[t]       + lnb[t])       * wa[t]
            + ((a1 - mu) * rstd * lng[t + 256] + lnb[t + 256]) * wa[t + 256]
            + ((a2 - mu) * rstd * lng[t + 512] + lnb[t + 512]) * wa[t + 512];
    float dot = block_sum(d, sred, t);
    if (t == 0) logits[b * NA + a] = dot + bat[a];
}

// ---------------- K5: BatchNorm1d over batch (training stats) ----------------
__global__ __launch_bounds__(64) void k_bn(const float* __restrict__ logits,
                                           const float* __restrict__ bng,
                                           const float* __restrict__ bnb,
                                           float* __restrict__ out) {
    const int a = threadIdx.x;
    if (a >= NA) return;
    float s = 0.f, s2 = 0.f;
    for (int b = 0; b < NB; ++b) {
        float v = logits[b * NA + a];
        s += v; s2 += v * v;
    }
    const float m = s * (1.0f / 64.0f);
    const float var = s2 * (1.0f / 64.0f) - m * m;
    const float rstd = rsqrtf(var + LNEPS);
    const float ga = bng[a], be = bnb[a];
    for (int b = 0; b < NB; ++b)
        out[b * NA + a] = (logits[b * NA + a] - m) * rstd * ga + be;
}

extern "C" void kernel_launch(void* const* d_in, const int* in_sizes, int n_in,
                              void* d_out, int out_size, void* d_ws, size_t ws_size,
                              hipStream_t stream) {
    const float* x     = (const float*)d_in[0];
    const float* ln_g  = (const float*)d_in[1];
    const float* ln_b  = (const float*)d_in[2];
    const float* w_at  = (const float*)d_in[3];
    const float* b_at  = (const float*)d_in[4];
    const float* bn_g  = (const float*)d_in[5];
    const float* bn_b  = (const float*)d_in[6];
    float* out = (float*)d_out;

    char* wsc = (char*)d_ws;
    const size_t XN = 64ull * 768 * 768 * 2;          // 75,497,472 B bf16 copy
    unsigned short* xn = (unsigned short*)wsc;
    float* norms  = (float*)(wsc + XN);                // 196608 B
    int*   bad    = (int*)(wsc + XN + 196608);         // 196608 B
    int*   inv    = (int*)(wsc + XN + 393216);         // 196608 B
    int*   counts = (int*)(wsc + XN + 589824);         // 256 B
    int*   Lval   = (int*)(wsc + XN + 590080);         // 256 B
    float* logits = (float*)(wsc + XN + 590336);       // 13056 B

    k_norms <<<NB * TN / 4, 256, 0, stream>>>(x, xn, norms, bad, Lval);
    k_gram  <<<21 * NB, 256, 0, stream>>>(xn, bad);
    k_filter<<<NB, 256, 0, stream>>>(bad, norms, inv, counts, Lval);
    k_head  <<<dim3(NA, NB), 256, 0, stream>>>(x, inv, counts, Lval,
                                               ln_g, ln_b, w_at, b_at, logits);
    k_bn    <<<1, 64, 0, stream>>>(logits, bn_g, bn_b, out);
}